// Round 4
// baseline (1358.512 us; speedup 1.0000x reference)
//
#include <hip/hip_runtime.h>
#include <stdint.h>

#define D 128
#define Ssz 10
#define WP 136   // LDS row pad (u16): 272B rows, 16B-aligned

typedef uint16_t u16;
typedef uint32_t u32;
typedef __attribute__((ext_vector_type(8))) short short8;
typedef __attribute__((ext_vector_type(4))) float f32x4;

__device__ __forceinline__ u16 f2bf(float f){
  u32 x = __float_as_uint(f);
  return (u16)((x + 0x7fffu + ((x >> 16) & 1u)) >> 16);   // RNE
}
__device__ __forceinline__ float bf2f(u16 u){ return __uint_as_float(((u32)u) << 16); }

// WT[n*K + k] = bf16(W[k*D + n])   (W is f32 [K][128])
__global__ __launch_bounds__(256) void transpose_k(const float* __restrict__ W,
                                                   u16* __restrict__ WT, int K){
  int i = blockIdx.x * 256 + threadIdx.x;
  if (i >= K * D) return;
  int n = i / K, k = i - n * K;
  WT[i] = f2bf(W[k * D + n]);
}

// out[m][n] = sum_k feats[clamp(idx[m])][k] * WT[n][k] + bias[n]
// grid.x = M/64, block 256 (4 waves x 16 rows each), N = 128 (8 n-tiles/wave)
// depth-4 A-prefetch ring: K assumed multiple of 128 (1024 / 2048 here).
__global__ __launch_bounds__(256) void proj_gemm(
    const float* __restrict__ feats, int K, int nfeat,
    const int* __restrict__ idx,
    const u16* __restrict__ WT,       // bf16 [128][K]
    const float* __restrict__ bias,   // f32 [128]
    u16* __restrict__ outb,           // bf16 [M][128] or null
    float* __restrict__ outf)         // f32  [M][128] or null
{
  int lane = threadIdx.x & 63;
  int wave = threadIdx.x >> 6;
  int quad = lane >> 4, l16 = lane & 15;
  int m0 = blockIdx.x * 64 + wave * 16;

  int row = idx[m0 + l16];
  row = min(max(row, 0), nfeat - 1);
  const float* aptr = feats + (long)row * K + quad * 8;

  f32x4 acc[8];
#pragma unroll
  for (int nt = 0; nt < 8; ++nt){
    float bv = bias[nt * 16 + l16];
    f32x4 t = {bv, bv, bv, bv};
    acc[nt] = t;
  }

  // prologue: fill 4-deep A ring (iterations 0..3)
  f32x4 ra[4][2];
#pragma unroll
  for (int j = 0; j < 4; ++j){
    ra[j][0] = *(const f32x4*)(aptr + j * 32);
    ra[j][1] = *(const f32x4*)(aptr + j * 32 + 4);
  }

  const u16* wptr = WT + (long)l16 * K + quad * 8;  // + nt*16*K per tile
  for (int base = 0; base < K; base += 128){
#pragma unroll
    for (int j = 0; j < 4; ++j){
      // convert current ring slot
      short8 a;
#pragma unroll
      for (int q = 0; q < 4; ++q){
        a[q]     = (short)f2bf(ra[j][0][q]);
        a[4 + q] = (short)f2bf(ra[j][1][q]);
      }
      // refill slot for iteration (base/32 + j + 4)
      int nk = base + 128 + j * 32;
      if (nk < K){
        ra[j][0] = *(const f32x4*)(aptr + nk);
        ra[j][1] = *(const f32x4*)(aptr + nk + 4);
      }
      const u16* wp = wptr + base + j * 32;
#pragma unroll
      for (int nt = 0; nt < 8; ++nt){
        short8 b = *(const short8*)(wp + (long)nt * 16 * K);
        acc[nt] = __builtin_amdgcn_mfma_f32_16x16x32_bf16(a, b, acc[nt], 0, 0, 0);
      }
    }
  }

#pragma unroll
  for (int nt = 0; nt < 8; ++nt){
    int col = nt * 16 + l16;
#pragma unroll
    for (int r = 0; r < 4; ++r){
      long o = (long)(m0 + quad * 4 + r) * D + col;
      if (outb) outb[o] = f2bf(acc[nt][r]);
      if (outf) outf[o] = acc[nt][r];
    }
  }
}

// out bf16[r][:] = tab f32[clamp(idx[r])][:]; 64 lanes/row, 2 elems/lane
__global__ __launch_bounds__(256) void gather_rows(
    const float* __restrict__ tab, const int* __restrict__ idx,
    u16* __restrict__ out, int nrows, int nfeat)
{
  int t = blockIdx.x * 256 + threadIdx.x;
  int r = t >> 6, c = t & 63;
  if (r >= nrows) return;
  int row = idx[r];
  row = min(max(row, 0), nfeat - 1);
  float v0 = tab[(long)row * D + 2 * c];
  float v1 = tab[(long)row * D + 2 * c + 1];
  ((u32*)out)[(long)r * 64 + c] = (u32)f2bf(v0) | ((u32)f2bf(v1) << 16);
}

// h_s = tanh(x_s @ Wx + h @ Wh + b) over s=0..9; agg = h_last (bf16)
// grid.x = CB/16; block 256 = 4 waves; wave w owns cols [32w, 32w+32)
// x loads for step s+1 prefetched during step s.
__global__ __launch_bounds__(256) void rnn_kernel(
    const u16* __restrict__ x,       // bf16 [CB*S][128]
    const float* __restrict__ Wx,    // f32 [128][128]
    const float* __restrict__ Wh,
    const float* __restrict__ bvec,  // f32 [128]
    u16* __restrict__ agg)           // bf16 [CB][128]
{
  __shared__ u16 WxT[D * WP];
  __shared__ u16 WhT[D * WP];
  __shared__ u16 hbuf[16 * WP];

  int tid = threadIdx.x;
  for (int i = tid; i < D * D; i += 256){
    int n = i >> 7, k = i & 127;
    WxT[n * WP + k] = f2bf(Wx[k * D + n]);
    WhT[n * WP + k] = f2bf(Wh[k * D + n]);
  }
  for (int i = tid; i < 16 * WP; i += 256) hbuf[i] = 0;  // h0 = zeros
  __syncthreads();

  int lane = tid & 63, wave = tid >> 6;
  int quad = lane >> 4, l16 = lane & 15;
  int b0 = blockIdx.x * 16;
  int n0 = wave * 32;

  // step-invariant weight B-fragments: 2 n-tiles x 4 k-steps x 2 mats
  short8 wxf[2][4], whf[2][4];
#pragma unroll
  for (int nt = 0; nt < 2; ++nt){
    int n = n0 + nt * 16 + l16;
#pragma unroll
    for (int ks = 0; ks < 4; ++ks){
      wxf[nt][ks] = *(const short8*)(&WxT[n * WP + ks * 32 + quad * 8]);
      whf[nt][ks] = *(const short8*)(&WhT[n * WP + ks * 32 + quad * 8]);
    }
  }
  float bias0 = bvec[n0 + l16];
  float bias1 = bvec[n0 + 16 + l16];

  const u16* xb = x + (long)(b0 + l16) * Ssz * D + quad * 8;

  short8 xc[4], xn[4];
#pragma unroll
  for (int ks = 0; ks < 4; ++ks) xc[ks] = *(const short8*)(xb + ks * 32);

  float hout[8];
  for (int s = 0; s < Ssz; ++s){
    short8 hf[4];
#pragma unroll
    for (int ks = 0; ks < 4; ++ks)
      hf[ks] = *(const short8*)(&hbuf[l16 * WP + ks * 32 + quad * 8]);
    if (s + 1 < Ssz){
#pragma unroll
      for (int ks = 0; ks < 4; ++ks) xn[ks] = *(const short8*)(xb + (s + 1) * D + ks * 32);
    }
    f32x4 acc0 = {bias0, bias0, bias0, bias0};
    f32x4 acc1 = {bias1, bias1, bias1, bias1};
#pragma unroll
    for (int ks = 0; ks < 4; ++ks){
      acc0 = __builtin_amdgcn_mfma_f32_16x16x32_bf16(xc[ks], wxf[0][ks], acc0, 0, 0, 0);
      acc0 = __builtin_amdgcn_mfma_f32_16x16x32_bf16(hf[ks], whf[0][ks], acc0, 0, 0, 0);
      acc1 = __builtin_amdgcn_mfma_f32_16x16x32_bf16(xc[ks], wxf[1][ks], acc1, 0, 0, 0);
      acc1 = __builtin_amdgcn_mfma_f32_16x16x32_bf16(hf[ks], whf[1][ks], acc1, 0, 0, 0);
    }
    __syncthreads();   // all waves done READING old h
#pragma unroll
    for (int r = 0; r < 4; ++r){
      float v0 = tanhf(acc0[r]);
      float v1 = tanhf(acc1[r]);
      hout[r] = v0; hout[4 + r] = v1;
      hbuf[(quad * 4 + r) * WP + n0 + l16]      = f2bf(v0);
      hbuf[(quad * 4 + r) * WP + n0 + 16 + l16] = f2bf(v1);
    }
    __syncthreads();   // new h visible
#pragma unroll
    for (int ks = 0; ks < 4; ++ks) xc[ks] = xn[ks];
  }

#pragma unroll
  for (int r = 0; r < 4; ++r){
    int row = b0 + quad * 4 + r;
    agg[(long)row * D + n0 + l16]      = f2bf(hout[r]);
    agg[(long)row * D + n0 + 16 + l16] = f2bf(hout[4 + r]);
  }
}

// scores_c = leaky( h.aw[:128] + cand_c.aw[128:] ), softmax over 4, combine.
// one 64-lane wave per (local) row; lane owns elements {2*lane, 2*lane+1}
__global__ __launch_bounds__(256) void att_kernel(
    const float* __restrict__ h,   // f32 [CB][128]
    const u16* __restrict__ agg,   // bf16 [3][CB][128]
    const float* __restrict__ aw,  // f32 [256]
    float* __restrict__ out,       // f32 [CB][128]
    int CB)
{
  int gt = blockIdx.x * 256 + threadIdx.x;
  int lane = gt & 63;
  int b = gt >> 6;
  int e = 2 * lane;

  float c[4][2];
  c[0][0] = h[(long)b * D + e];
  c[0][1] = h[(long)b * D + e + 1];
#pragma unroll
  for (int t = 0; t < 3; ++t){
    c[t + 1][0] = bf2f(agg[((long)t * CB + b) * D + e]);
    c[t + 1][1] = bf2f(agg[((long)t * CB + b) * D + e + 1]);
  }
  float as0 = aw[e],     as1 = aw[e + 1];
  float ac0 = aw[D + e], ac1 = aw[D + e + 1];

  float selfp = c[0][0] * as0 + c[0][1] * as1;
  float sc[4];
#pragma unroll
  for (int cc = 0; cc < 4; ++cc) sc[cc] = selfp + c[cc][0] * ac0 + c[cc][1] * ac1;
#pragma unroll
  for (int off = 32; off >= 1; off >>= 1){
#pragma unroll
    for (int cc = 0; cc < 4; ++cc) sc[cc] += __shfl_xor(sc[cc], off, 64);
  }
#pragma unroll
  for (int cc = 0; cc < 4; ++cc) sc[cc] = sc[cc] > 0.f ? sc[cc] : 0.01f * sc[cc];

  float mx = fmaxf(fmaxf(sc[0], sc[1]), fmaxf(sc[2], sc[3]));
  float ex[4], ssum = 0.f;
#pragma unroll
  for (int cc = 0; cc < 4; ++cc){ ex[cc] = expf(sc[cc] - mx); ssum += ex[cc]; }
  float o0 = 0.f, o1 = 0.f;
#pragma unroll
  for (int cc = 0; cc < 4; ++cc){
    float a = ex[cc] / ssum;
    o0 += a * c[cc][0];
    o1 += a * c[cc][1];
  }
  out[(long)b * D + e]     = o0;
  out[(long)b * D + e + 1] = o1;
}

extern "C" void kernel_launch(void* const* d_in, const int* in_sizes, int n_in,
                              void* d_out, int out_size, void* d_ws, size_t ws_size,
                              hipStream_t stream)
{
  const float* drug_feats = (const float*)d_in[0];   // [4000][1024]
  const float* gene_feats = (const float*)d_in[1];   // [20000][2048]
  const float* cell_tab   = (const float*)d_in[2];   // [2000][128]
  const float* W_drug     = (const float*)d_in[3];   // [1024][128]
  const float* b_drug     = (const float*)d_in[4];   // [128]
  const float* W_gene     = (const float*)d_in[5];   // [2048][128]
  const float* b_gene     = (const float*)d_in[6];   // [128]
  const float* rnn_Wx     = (const float*)d_in[7];   // [2][3][128][128]
  const float* rnn_Wh     = (const float*)d_in[8];
  const float* rnn_b      = (const float*)d_in[9];   // [2][3][128]
  const float* att_w      = (const float*)d_in[10];  // [2][256]
  const int* center_ids   = (const int*)d_in[11];    // [4096]
  const int* cell_neigh   = (const int*)d_in[12];    // [2][4096][10]
  const int* drug_neigh   = (const int*)d_in[13];
  const int* gene_neigh   = (const int*)d_in[14];

  // ws (u16 elems): WdT [128*1024] | WgT [128*2048] | agg [3*CB*128] | x [CB*10*128]
  // bytes needed = 786432 + 3328*CB; CB from ws_size (constant per call).
  int CB = 4096;
  while (CB > 64){
    size_t need = 786432 + (size_t)3328 * CB;
    if (need <= ws_size) break;
    CB >>= 1;
  }

  u16* ws  = (u16*)d_ws;
  u16* WdT = ws;
  u16* WgT = WdT + 128 * 1024;
  u16* agg = WgT + 128 * 2048;
  u16* x   = agg + (size_t)3 * CB * 128;
  float* h = (float*)d_out;               // f32 [4096][128] — h lives in d_out

  transpose_k<<<(1024 * D + 255) / 256, 256, 0, stream>>>(W_drug, WdT, 1024);
  transpose_k<<<(2048 * D + 255) / 256, 256, 0, stream>>>(W_gene, WgT, 2048);

  for (int b0 = 0; b0 < 4096; b0 += CB){
    // h0 = drug_feats[center_ids] @ W_drug + b_drug  (f32 into d_out rows)
    proj_gemm<<<CB / 64, 256, 0, stream>>>(drug_feats, 1024, 4000,
                                           center_ids + b0, WdT, b_drug,
                                           (u16*)nullptr, h + (size_t)b0 * D);
    for (int l = 0; l < 2; ++l){
      const int* cn = cell_neigh + ((size_t)l * 4096 + b0) * Ssz;
      const int* dn = drug_neigh + ((size_t)l * 4096 + b0) * Ssz;
      const int* gn = gene_neigh + ((size_t)l * 4096 + b0) * Ssz;
      const float* Wx = rnn_Wx + (size_t)l * 3 * D * D;
      const float* Wh = rnn_Wh + (size_t)l * 3 * D * D;
      const float* bb = rnn_b  + (size_t)l * 3 * D;

      // type 0: cell (raw table rows)
      gather_rows<<<CB * Ssz / 4, 256, 0, stream>>>(cell_tab, cn, x, CB * Ssz, 2000);
      rnn_kernel<<<CB / 16, 256, 0, stream>>>(x, Wx, Wh, bb, agg);
      // type 1: drug (gather + project)
      proj_gemm<<<CB * Ssz / 64, 256, 0, stream>>>(drug_feats, 1024, 4000, dn,
                                                   WdT, b_drug, x, (float*)nullptr);
      rnn_kernel<<<CB / 16, 256, 0, stream>>>(x, Wx + D * D, Wh + D * D, bb + D,
                                              agg + (size_t)CB * D);
      // type 2: gene
      proj_gemm<<<CB * Ssz / 64, 256, 0, stream>>>(gene_feats, 2048, 20000, gn,
                                                   WgT, b_gene, x, (float*)nullptr);
      rnn_kernel<<<CB / 16, 256, 0, stream>>>(x, Wx + 2 * D * D, Wh + 2 * D * D,
                                              bb + 2 * D, agg + (size_t)2 * CB * D);
      // attention combine (in-place over this chunk's h rows)
      att_kernel<<<CB / 4, 256, 0, stream>>>(h + (size_t)b0 * D, agg,
                                             att_w + (size_t)l * 2 * D,
                                             h + (size_t)b0 * D, CB);
    }
  }
}

// Round 5
// 986.967 us; speedup vs baseline: 1.3765x; 1.3765x over previous
//
#include <hip/hip_runtime.h>
#include <stdint.h>

#define D 128
#define Ssz 10
#define WP 136   // LDS row pad (u16) for rnn staging

typedef uint16_t u16;
typedef uint32_t u32;
typedef __attribute__((ext_vector_type(8))) short short8;
typedef __attribute__((ext_vector_type(4))) float f32x4;

#define AS1U32(p) ((const __attribute__((address_space(1))) u32*)(p))
#define AS3U32(p) ((__attribute__((address_space(3))) u32*)(p))

__device__ __forceinline__ u16 f2bf(float f){
  u32 x = __float_as_uint(f);
  return (u16)((x + 0x7fffu + ((x >> 16) & 1u)) >> 16);   // RNE
}
__device__ __forceinline__ float bf2f(u16 u){ return __uint_as_float(((u32)u) << 16); }

// WT[n*K + k] = bf16(W[k*D + n])   (W is f32 [K][128])
__global__ __launch_bounds__(256) void transpose_k(const float* __restrict__ W,
                                                   u16* __restrict__ WT, int K){
  int i = blockIdx.x * 256 + threadIdx.x;
  if (i >= K * D) return;
  int n = i / K, k = i - n * K;
  WT[i] = f2bf(W[k * D + n]);
}

// out[m][n] = sum_k feats[clamp(idx[m])][k] * WT[n][k] + bias[n]
// grid.x = M/64, block 256 (4 waves x 16 rows each), N = 128 (8 n-tiles/wave).
// B k-chunks (128x128 bf16 = 32 KB) staged via global_load_lds with XOR-16
// chunk swizzle; A double-buffered in registers one chunk ahead.
__global__ __launch_bounds__(256) void proj_gemm(
    const float* __restrict__ feats, int K, int nfeat,
    const int* __restrict__ idx,
    const u16* __restrict__ WT,       // bf16 [128][K]
    const float* __restrict__ bias,   // f32 [128]
    u16* __restrict__ outb,           // bf16 [M][128] or null
    float* __restrict__ outf)         // f32  [M][128] or null
{
  __shared__ u16 Bt[128 * 128];       // [n][p] p = swizzled 8-elem chunk pos

  int lane = threadIdx.x & 63;
  int wave = threadIdx.x >> 6;
  int quad = lane >> 4, l16 = lane & 15;
  int m0 = blockIdx.x * 64 + wave * 16;

  int row = idx[m0 + l16];
  row = min(max(row, 0), nfeat - 1);
  const float* aptr = feats + (long)row * K + quad * 8;

  // staging geometry (per lane, per j-instruction): instr i = wave*8+j covers
  // rows i*4+(lane>>4); lane writes LDS chunk-pos p=lane&15 holding global
  // chunk c = p ^ (n&15).
  int st_nrow = wave * 32 + (lane >> 4);          // + j*4
  int st_p    = lane & 15;

  f32x4 acc[8];
#pragma unroll
  for (int nt = 0; nt < 8; ++nt){
    float bv = bias[nt * 16 + l16];
    f32x4 t = {bv, bv, bv, bv};
    acc[nt] = t;
  }

  // A chunk 0 into buffer 0
  f32x4 af[2][4][2];
#pragma unroll
  for (int ks = 0; ks < 4; ++ks){
    af[0][ks][0] = *(const f32x4*)(aptr + ks * 32);
    af[0][ks][1] = *(const f32x4*)(aptr + ks * 32 + 4);
  }

  int cur = 0;
  for (int kc = 0; kc < K; kc += 128){
    // stage B chunk kc -> LDS (8 x 16B-per-lane instructions per wave)
#pragma unroll
    for (int j = 0; j < 8; ++j){
      int n = st_nrow + j * 4;
      int c = st_p ^ (n & 15);
      const u16* g = WT + (long)n * K + kc + c * 8;
      __builtin_amdgcn_global_load_lds(AS1U32(g),
                                       AS3U32(&Bt[(wave * 8 + j) * 512]),
                                       16, 0, 0);
    }
    // prefetch next A chunk into alternate buffer
    if (kc + 128 < K){
#pragma unroll
      for (int ks = 0; ks < 4; ++ks){
        af[cur ^ 1][ks][0] = *(const f32x4*)(aptr + kc + 128 + ks * 32);
        af[cur ^ 1][ks][1] = *(const f32x4*)(aptr + kc + 128 + ks * 32 + 4);
      }
    }
    __syncthreads();   // drains vmcnt -> LDS tile + current A ready

#pragma unroll
    for (int ks = 0; ks < 4; ++ks){
      short8 a;
#pragma unroll
      for (int q = 0; q < 4; ++q){
        a[q]     = (short)f2bf(af[cur][ks][0][q]);
        a[4 + q] = (short)f2bf(af[cur][ks][1][q]);
      }
#pragma unroll
      for (int nt = 0; nt < 8; ++nt){
        int n = nt * 16 + l16;
        int p = (ks * 4 + quad) ^ l16;
        short8 b = *(const short8*)(&Bt[n * 128 + p * 8]);
        acc[nt] = __builtin_amdgcn_mfma_f32_16x16x32_bf16(a, b, acc[nt], 0, 0, 0);
      }
    }
    __syncthreads();   // LDS reads done before next stage overwrites
    cur ^= 1;
  }

#pragma unroll
  for (int nt = 0; nt < 8; ++nt){
    int col = nt * 16 + l16;
#pragma unroll
    for (int r = 0; r < 4; ++r){
      long o = (long)(m0 + quad * 4 + r) * D + col;
      if (outb) outb[o] = f2bf(acc[nt][r]);
      if (outf) outf[o] = acc[nt][r];
    }
  }
}

// out bf16[r][:] = tab f32[clamp(idx[r])][:]; 64 lanes/row, 2 elems/lane
__global__ __launch_bounds__(256) void gather_rows(
    const float* __restrict__ tab, const int* __restrict__ idx,
    u16* __restrict__ out, int nrows, int nfeat)
{
  int t = blockIdx.x * 256 + threadIdx.x;
  int r = t >> 6, c = t & 63;
  if (r >= nrows) return;
  int row = idx[r];
  row = min(max(row, 0), nfeat - 1);
  float v0 = tab[(long)row * D + 2 * c];
  float v1 = tab[(long)row * D + 2 * c + 1];
  ((u32*)out)[(long)r * 64 + c] = (u32)f2bf(v0) | ((u32)f2bf(v1) << 16);
}

// h_s = tanh(x_s @ Wx + h @ Wh + b) over s=0..9; agg = h_last (bf16)
// grid.x = CB/16; block 256 = 4 waves; wave w owns cols [32w, 32w+32)
__global__ __launch_bounds__(256) void rnn_kernel(
    const u16* __restrict__ x,       // bf16 [CB*S][128]
    const float* __restrict__ Wx,    // f32 [128][128]
    const float* __restrict__ Wh,
    const float* __restrict__ bvec,  // f32 [128]
    u16* __restrict__ agg)           // bf16 [CB][128]
{
  __shared__ u16 WxT[D * WP];
  __shared__ u16 WhT[D * WP];
  __shared__ u16 hbuf[16 * WP];

  int tid = threadIdx.x;
  for (int i = tid; i < D * D; i += 256){
    int n = i >> 7, k = i & 127;
    WxT[n * WP + k] = f2bf(Wx[k * D + n]);
    WhT[n * WP + k] = f2bf(Wh[k * D + n]);
  }
  for (int i = tid; i < 16 * WP; i += 256) hbuf[i] = 0;  // h0 = zeros
  __syncthreads();

  int lane = tid & 63, wave = tid >> 6;
  int quad = lane >> 4, l16 = lane & 15;
  int b0 = blockIdx.x * 16;
  int n0 = wave * 32;

  // step-invariant weight B-fragments: 2 n-tiles x 4 k-steps x 2 mats
  short8 wxf[2][4], whf[2][4];
#pragma unroll
  for (int nt = 0; nt < 2; ++nt){
    int n = n0 + nt * 16 + l16;
#pragma unroll
    for (int ks = 0; ks < 4; ++ks){
      wxf[nt][ks] = *(const short8*)(&WxT[n * WP + ks * 32 + quad * 8]);
      whf[nt][ks] = *(const short8*)(&WhT[n * WP + ks * 32 + quad * 8]);
    }
  }
  float bias0 = bvec[n0 + l16];
  float bias1 = bvec[n0 + 16 + l16];

  const u16* xb = x + (long)(b0 + l16) * Ssz * D + quad * 8;

  short8 xc[4], xn[4];
#pragma unroll
  for (int ks = 0; ks < 4; ++ks) xc[ks] = *(const short8*)(xb + ks * 32);

  float hout[8];
  for (int s = 0; s < Ssz; ++s){
    short8 hf[4];
#pragma unroll
    for (int ks = 0; ks < 4; ++ks)
      hf[ks] = *(const short8*)(&hbuf[l16 * WP + ks * 32 + quad * 8]);
    if (s + 1 < Ssz){
#pragma unroll
      for (int ks = 0; ks < 4; ++ks) xn[ks] = *(const short8*)(xb + (s + 1) * D + ks * 32);
    }
    f32x4 acc0 = {bias0, bias0, bias0, bias0};
    f32x4 acc1 = {bias1, bias1, bias1, bias1};
#pragma unroll
    for (int ks = 0; ks < 4; ++ks){
      acc0 = __builtin_amdgcn_mfma_f32_16x16x32_bf16(xc[ks], wxf[0][ks], acc0, 0, 0, 0);
      acc0 = __builtin_amdgcn_mfma_f32_16x16x32_bf16(hf[ks], whf[0][ks], acc0, 0, 0, 0);
      acc1 = __builtin_amdgcn_mfma_f32_16x16x32_bf16(xc[ks], wxf[1][ks], acc1, 0, 0, 0);
      acc1 = __builtin_amdgcn_mfma_f32_16x16x32_bf16(hf[ks], whf[1][ks], acc1, 0, 0, 0);
    }
    __syncthreads();   // all waves done READING old h
#pragma unroll
    for (int r = 0; r < 4; ++r){
      float v0 = tanhf(acc0[r]);
      float v1 = tanhf(acc1[r]);
      hout[r] = v0; hout[4 + r] = v1;
      hbuf[(quad * 4 + r) * WP + n0 + l16]      = f2bf(v0);
      hbuf[(quad * 4 + r) * WP + n0 + 16 + l16] = f2bf(v1);
    }
    __syncthreads();   // new h visible
#pragma unroll
    for (int ks = 0; ks < 4; ++ks) xc[ks] = xn[ks];
  }

#pragma unroll
  for (int r = 0; r < 4; ++r){
    int row = b0 + quad * 4 + r;
    agg[(long)row * D + n0 + l16]      = f2bf(hout[r]);
    agg[(long)row * D + n0 + 16 + l16] = f2bf(hout[4 + r]);
  }
}

// scores_c = leaky( h.aw[:128] + cand_c.aw[128:] ), softmax over 4, combine.
// one 64-lane wave per (local) row; lane owns elements {2*lane, 2*lane+1}
__global__ __launch_bounds__(256) void att_kernel(
    const float* __restrict__ h,   // f32 [CB][128]
    const u16* __restrict__ agg,   // bf16 [3][CB][128]
    const float* __restrict__ aw,  // f32 [256]
    float* __restrict__ out,       // f32 [CB][128]
    int CB)
{
  int gt = blockIdx.x * 256 + threadIdx.x;
  int lane = gt & 63;
  int b = gt >> 6;
  int e = 2 * lane;

  float c[4][2];
  c[0][0] = h[(long)b * D + e];
  c[0][1] = h[(long)b * D + e + 1];
#pragma unroll
  for (int t = 0; t < 3; ++t){
    c[t + 1][0] = bf2f(agg[((long)t * CB + b) * D + e]);
    c[t + 1][1] = bf2f(agg[((long)t * CB + b) * D + e + 1]);
  }
  float as0 = aw[e],     as1 = aw[e + 1];
  float ac0 = aw[D + e], ac1 = aw[D + e + 1];

  float selfp = c[0][0] * as0 + c[0][1] * as1;
  float sc[4];
#pragma unroll
  for (int cc = 0; cc < 4; ++cc) sc[cc] = selfp + c[cc][0] * ac0 + c[cc][1] * ac1;
#pragma unroll
  for (int off = 32; off >= 1; off >>= 1){
#pragma unroll
    for (int cc = 0; cc < 4; ++cc) sc[cc] += __shfl_xor(sc[cc], off, 64);
  }
#pragma unroll
  for (int cc = 0; cc < 4; ++cc) sc[cc] = sc[cc] > 0.f ? sc[cc] : 0.01f * sc[cc];

  float mx = fmaxf(fmaxf(sc[0], sc[1]), fmaxf(sc[2], sc[3]));
  float ex[4], ssum = 0.f;
#pragma unroll
  for (int cc = 0; cc < 4; ++cc){ ex[cc] = expf(sc[cc] - mx); ssum += ex[cc]; }
  float o0 = 0.f, o1 = 0.f;
#pragma unroll
  for (int cc = 0; cc < 4; ++cc){
    float a = ex[cc] / ssum;
    o0 += a * c[cc][0];
    o1 += a * c[cc][1];
  }
  out[(long)b * D + e]     = o0;
  out[(long)b * D + e + 1] = o1;
}

extern "C" void kernel_launch(void* const* d_in, const int* in_sizes, int n_in,
                              void* d_out, int out_size, void* d_ws, size_t ws_size,
                              hipStream_t stream)
{
  const float* drug_feats = (const float*)d_in[0];   // [4000][1024]
  const float* gene_feats = (const float*)d_in[1];   // [20000][2048]
  const float* cell_tab   = (const float*)d_in[2];   // [2000][128]
  const float* W_drug     = (const float*)d_in[3];   // [1024][128]
  const float* b_drug     = (const float*)d_in[4];   // [128]
  const float* W_gene     = (const float*)d_in[5];   // [2048][128]
  const float* b_gene     = (const float*)d_in[6];   // [128]
  const float* rnn_Wx     = (const float*)d_in[7];   // [2][3][128][128]
  const float* rnn_Wh     = (const float*)d_in[8];
  const float* rnn_b      = (const float*)d_in[9];   // [2][3][128]
  const float* att_w      = (const float*)d_in[10];  // [2][256]
  const int* center_ids   = (const int*)d_in[11];    // [4096]
  const int* cell_neigh   = (const int*)d_in[12];    // [2][4096][10]
  const int* drug_neigh   = (const int*)d_in[13];
  const int* gene_neigh   = (const int*)d_in[14];

  // ws (u16 elems): WdT [128*1024] | WgT [128*2048] | agg [3*CB*128] | x [CB*10*128]
  // bytes needed = 786432 + 3328*CB; CB from ws_size (constant per call).
  int CB = 4096;
  while (CB > 64){
    size_t need = 786432 + (size_t)3328 * CB;
    if (need <= ws_size) break;
    CB >>= 1;
  }

  u16* ws  = (u16*)d_ws;
  u16* WdT = ws;
  u16* WgT = WdT + 128 * 1024;
  u16* agg = WgT + 128 * 2048;
  u16* x   = agg + (size_t)3 * CB * 128;
  float* h = (float*)d_out;               // f32 [4096][128] — h lives in d_out

  transpose_k<<<(1024 * D + 255) / 256, 256, 0, stream>>>(W_drug, WdT, 1024);
  transpose_k<<<(2048 * D + 255) / 256, 256, 0, stream>>>(W_gene, WgT, 2048);

  for (int b0 = 0; b0 < 4096; b0 += CB){
    // h0 = drug_feats[center_ids] @ W_drug + b_drug  (f32 into d_out rows)
    proj_gemm<<<CB / 64, 256, 0, stream>>>(drug_feats, 1024, 4000,
                                           center_ids + b0, WdT, b_drug,
                                           (u16*)nullptr, h + (size_t)b0 * D);
    for (int l = 0; l < 2; ++l){
      const int* cn = cell_neigh + ((size_t)l * 4096 + b0) * Ssz;
      const int* dn = drug_neigh + ((size_t)l * 4096 + b0) * Ssz;
      const int* gn = gene_neigh + ((size_t)l * 4096 + b0) * Ssz;
      const float* Wx = rnn_Wx + (size_t)l * 3 * D * D;
      const float* Wh = rnn_Wh + (size_t)l * 3 * D * D;
      const float* bb = rnn_b  + (size_t)l * 3 * D;

      // type 0: cell (raw table rows)
      gather_rows<<<CB * Ssz / 4, 256, 0, stream>>>(cell_tab, cn, x, CB * Ssz, 2000);
      rnn_kernel<<<CB / 16, 256, 0, stream>>>(x, Wx, Wh, bb, agg);
      // type 1: drug (gather + project)
      proj_gemm<<<CB * Ssz / 64, 256, 0, stream>>>(drug_feats, 1024, 4000, dn,
                                                   WdT, b_drug, x, (float*)nullptr);
      rnn_kernel<<<CB / 16, 256, 0, stream>>>(x, Wx + D * D, Wh + D * D, bb + D,
                                              agg + (size_t)CB * D);
      // type 2: gene
      proj_gemm<<<CB * Ssz / 64, 256, 0, stream>>>(gene_feats, 2048, 20000, gn,
                                                   WgT, b_gene, x, (float*)nullptr);
      rnn_kernel<<<CB / 16, 256, 0, stream>>>(x, Wx + 2 * D * D, Wh + 2 * D * D,
                                              bb + 2 * D, agg + (size_t)2 * CB * D);
      // attention combine (in-place over this chunk's h rows)
      att_kernel<<<CB / 4, 256, 0, stream>>>(h + (size_t)b0 * D, agg,
                                             att_w + (size_t)l * 2 * D,
                                             h + (size_t)b0 * D, CB);
    }
  }
}

// Round 6
// 682.364 us; speedup vs baseline: 1.9909x; 1.4464x over previous
//
#include <hip/hip_runtime.h>
#include <stdint.h>

#define D 128
#define Ssz 10
#define WP 136   // LDS row pad (u16) for rnn staging

typedef uint16_t u16;
typedef uint32_t u32;
typedef __attribute__((ext_vector_type(8))) short short8;
typedef __attribute__((ext_vector_type(4))) float f32x4;

#define AS1U32(p) ((const __attribute__((address_space(1))) u32*)(p))
#define AS3U32(p) ((__attribute__((address_space(3))) u32*)(p))

__device__ __forceinline__ u16 f2bf(float f){
  u32 x = __float_as_uint(f);
  return (u16)((x + 0x7fffu + ((x >> 16) & 1u)) >> 16);   // RNE
}
__device__ __forceinline__ float bf2f(u16 u){ return __uint_as_float(((u32)u) << 16); }

// WT[n*K + k] = bf16(W[k*D + n])   (W is f32 [K][128])
__global__ __launch_bounds__(256) void transpose_k(const float* __restrict__ W,
                                                   u16* __restrict__ WT, int K){
  int i = blockIdx.x * 256 + threadIdx.x;
  if (i >= K * D) return;
  int n = i / K, k = i - n * K;
  WT[i] = f2bf(W[k * D + n]);
}

// out[m][n] = sum_k feats[clamp(idx[m])][k] * WT[n][k] + bias[n]
// grid.x = M/64, block 256 (4 waves x 16 rows each), N = 128 (8 n-tiles/wave).
// B k-chunks (128x128 bf16 = 32 KB) staged via global_load_lds (XOR-16 chunk
// swizzle); A double-buffered in registers with COMPILE-TIME phase (2x unroll
// of the k-chunk loop — runtime-indexed buffers spill to scratch, R5 lesson).
__global__ __launch_bounds__(256) void proj_gemm(
    const float* __restrict__ feats, int K, int nfeat,
    const int* __restrict__ idx,
    const u16* __restrict__ WT,       // bf16 [128][K]
    const float* __restrict__ bias,   // f32 [128]
    u16* __restrict__ outb,           // bf16 [M][128] or null
    float* __restrict__ outf)         // f32  [M][128] or null
{
  __shared__ u16 Bt[128 * 128];       // [n][p] p = swizzled 8-elem chunk pos

  int lane = threadIdx.x & 63;
  int wave = threadIdx.x >> 6;
  int quad = lane >> 4, l16 = lane & 15;
  int m0 = blockIdx.x * 64 + wave * 16;

  int row = idx[m0 + l16];
  row = min(max(row, 0), nfeat - 1);
  const float* aptr = feats + (long)row * K + quad * 8;

  int st_nrow = wave * 32 + (lane >> 4);          // + j*4 per staging instr
  int st_p    = lane & 15;

  f32x4 acc[8];
#pragma unroll
  for (int nt = 0; nt < 8; ++nt){
    float bv = bias[nt * 16 + l16];
    f32x4 t = {bv, bv, bv, bv};
    acc[nt] = t;
  }

  f32x4 afA[4][2], afB[4][2];
#pragma unroll
  for (int ks = 0; ks < 4; ++ks){
    afA[ks][0] = *(const f32x4*)(aptr + ks * 32);
    afA[ks][1] = *(const f32x4*)(aptr + ks * 32 + 4);
  }

  auto chunk_step = [&](f32x4 (&acur)[4][2], f32x4 (&anxt)[4][2], int kc) {
    // stage B chunk kc -> LDS (8 x 16B-per-lane instructions per wave)
#pragma unroll
    for (int j = 0; j < 8; ++j){
      int n = st_nrow + j * 4;
      int c = st_p ^ (n & 15);
      const u16* g = WT + (long)n * K + kc + c * 8;
      __builtin_amdgcn_global_load_lds(AS1U32(g),
                                       AS3U32(&Bt[(wave * 8 + j) * 512]),
                                       16, 0, 0);
    }
    // prefetch next A chunk into the alternate (named) buffer
    if (kc + 128 < K){
#pragma unroll
      for (int ks = 0; ks < 4; ++ks){
        anxt[ks][0] = *(const f32x4*)(aptr + kc + 128 + ks * 32);
        anxt[ks][1] = *(const f32x4*)(aptr + kc + 128 + ks * 32 + 4);
      }
    }
    __syncthreads();   // drains vmcnt -> LDS tile + current A ready

#pragma unroll
    for (int ks = 0; ks < 4; ++ks){
      short8 a;
#pragma unroll
      for (int q = 0; q < 4; ++q){
        a[q]     = (short)f2bf(acur[ks][0][q]);
        a[4 + q] = (short)f2bf(acur[ks][1][q]);
      }
#pragma unroll
      for (int nt = 0; nt < 8; ++nt){
        int n = nt * 16 + l16;
        int p = (ks * 4 + quad) ^ l16;
        short8 b = *(const short8*)(&Bt[n * 128 + p * 8]);
        acc[nt] = __builtin_amdgcn_mfma_f32_16x16x32_bf16(a, b, acc[nt], 0, 0, 0);
      }
    }
    __syncthreads();   // LDS reads done before next stage overwrites
  };

  for (int kc = 0; kc < K; kc += 256){
    chunk_step(afA, afB, kc);
    chunk_step(afB, afA, kc + 128);
  }

#pragma unroll
  for (int nt = 0; nt < 8; ++nt){
    int col = nt * 16 + l16;
#pragma unroll
    for (int r = 0; r < 4; ++r){
      long o = (long)(m0 + quad * 4 + r) * D + col;
      if (outb) outb[o] = f2bf(acc[nt][r]);
      if (outf) outf[o] = acc[nt][r];
    }
  }
}

// out bf16[r][:] = tab f32[clamp(idx[r])][:]; 64 lanes/row, 2 elems/lane
__global__ __launch_bounds__(256) void gather_rows(
    const float* __restrict__ tab, const int* __restrict__ idx,
    u16* __restrict__ out, int nrows, int nfeat)
{
  int t = blockIdx.x * 256 + threadIdx.x;
  int r = t >> 6, c = t & 63;
  if (r >= nrows) return;
  int row = idx[r];
  row = min(max(row, 0), nfeat - 1);
  float v0 = tab[(long)row * D + 2 * c];
  float v1 = tab[(long)row * D + 2 * c + 1];
  ((u32*)out)[(long)r * 64 + c] = (u32)f2bf(v0) | ((u32)f2bf(v1) << 16);
}

// h_s = tanh(x_s @ Wx + h @ Wh + b) over s=0..9; agg = h_last (bf16)
// grid.x = CB/16; block 256 = 4 waves; wave w owns cols [32w, 32w+32)
__global__ __launch_bounds__(256) void rnn_kernel(
    const u16* __restrict__ x,       // bf16 [CB*S][128]
    const float* __restrict__ Wx,    // f32 [128][128]
    const float* __restrict__ Wh,
    const float* __restrict__ bvec,  // f32 [128]
    u16* __restrict__ agg)           // bf16 [CB][128]
{
  __shared__ u16 WxT[D * WP];
  __shared__ u16 WhT[D * WP];
  __shared__ u16 hbuf[16 * WP];

  int tid = threadIdx.x;
  for (int i = tid; i < D * D; i += 256){
    int n = i >> 7, k = i & 127;
    WxT[n * WP + k] = f2bf(Wx[k * D + n]);
    WhT[n * WP + k] = f2bf(Wh[k * D + n]);
  }
  for (int i = tid; i < 16 * WP; i += 256) hbuf[i] = 0;  // h0 = zeros
  __syncthreads();

  int lane = tid & 63, wave = tid >> 6;
  int quad = lane >> 4, l16 = lane & 15;
  int b0 = blockIdx.x * 16;
  int n0 = wave * 32;

  // step-invariant weight B-fragments: 2 n-tiles x 4 k-steps x 2 mats
  short8 wxf[2][4], whf[2][4];
#pragma unroll
  for (int nt = 0; nt < 2; ++nt){
    int n = n0 + nt * 16 + l16;
#pragma unroll
    for (int ks = 0; ks < 4; ++ks){
      wxf[nt][ks] = *(const short8*)(&WxT[n * WP + ks * 32 + quad * 8]);
      whf[nt][ks] = *(const short8*)(&WhT[n * WP + ks * 32 + quad * 8]);
    }
  }
  float bias0 = bvec[n0 + l16];
  float bias1 = bvec[n0 + 16 + l16];

  const u16* xb = x + (long)(b0 + l16) * Ssz * D + quad * 8;

  short8 xc[4], xn[4];
#pragma unroll
  for (int ks = 0; ks < 4; ++ks) xc[ks] = *(const short8*)(xb + ks * 32);

  float hout[8];
  for (int s = 0; s < Ssz; ++s){
    short8 hf[4];
#pragma unroll
    for (int ks = 0; ks < 4; ++ks)
      hf[ks] = *(const short8*)(&hbuf[l16 * WP + ks * 32 + quad * 8]);
    if (s + 1 < Ssz){
#pragma unroll
      for (int ks = 0; ks < 4; ++ks) xn[ks] = *(const short8*)(xb + (s + 1) * D + ks * 32);
    }
    f32x4 acc0 = {bias0, bias0, bias0, bias0};
    f32x4 acc1 = {bias1, bias1, bias1, bias1};
#pragma unroll
    for (int ks = 0; ks < 4; ++ks){
      acc0 = __builtin_amdgcn_mfma_f32_16x16x32_bf16(xc[ks], wxf[0][ks], acc0, 0, 0, 0);
      acc0 = __builtin_amdgcn_mfma_f32_16x16x32_bf16(hf[ks], whf[0][ks], acc0, 0, 0, 0);
      acc1 = __builtin_amdgcn_mfma_f32_16x16x32_bf16(xc[ks], wxf[1][ks], acc1, 0, 0, 0);
      acc1 = __builtin_amdgcn_mfma_f32_16x16x32_bf16(hf[ks], whf[1][ks], acc1, 0, 0, 0);
    }
    __syncthreads();   // all waves done READING old h
#pragma unroll
    for (int r = 0; r < 4; ++r){
      float v0 = tanhf(acc0[r]);
      float v1 = tanhf(acc1[r]);
      hout[r] = v0; hout[4 + r] = v1;
      hbuf[(quad * 4 + r) * WP + n0 + l16]      = f2bf(v0);
      hbuf[(quad * 4 + r) * WP + n0 + 16 + l16] = f2bf(v1);
    }
    __syncthreads();   // new h visible
#pragma unroll
    for (int ks = 0; ks < 4; ++ks) xc[ks] = xn[ks];
  }

#pragma unroll
  for (int r = 0; r < 4; ++r){
    int row = b0 + quad * 4 + r;
    agg[(long)row * D + n0 + l16]      = f2bf(hout[r]);
    agg[(long)row * D + n0 + 16 + l16] = f2bf(hout[4 + r]);
  }
}

// scores_c = leaky( h.aw[:128] + cand_c.aw[128:] ), softmax over 4, combine.
// one 64-lane wave per (local) row; lane owns elements {2*lane, 2*lane+1}
__global__ __launch_bounds__(256) void att_kernel(
    const float* __restrict__ h,   // f32 [CB][128]
    const u16* __restrict__ agg,   // bf16 [3][CB][128]
    const float* __restrict__ aw,  // f32 [256]
    float* __restrict__ out,       // f32 [CB][128]
    int CB)
{
  int gt = blockIdx.x * 256 + threadIdx.x;
  int lane = gt & 63;
  int b = gt >> 6;
  int e = 2 * lane;

  float c[4][2];
  c[0][0] = h[(long)b * D + e];
  c[0][1] = h[(long)b * D + e + 1];
#pragma unroll
  for (int t = 0; t < 3; ++t){
    c[t + 1][0] = bf2f(agg[((long)t * CB + b) * D + e]);
    c[t + 1][1] = bf2f(agg[((long)t * CB + b) * D + e + 1]);
  }
  float as0 = aw[e],     as1 = aw[e + 1];
  float ac0 = aw[D + e], ac1 = aw[D + e + 1];

  float selfp = c[0][0] * as0 + c[0][1] * as1;
  float sc[4];
#pragma unroll
  for (int cc = 0; cc < 4; ++cc) sc[cc] = selfp + c[cc][0] * ac0 + c[cc][1] * ac1;
#pragma unroll
  for (int off = 32; off >= 1; off >>= 1){
#pragma unroll
    for (int cc = 0; cc < 4; ++cc) sc[cc] += __shfl_xor(sc[cc], off, 64);
  }
#pragma unroll
  for (int cc = 0; cc < 4; ++cc) sc[cc] = sc[cc] > 0.f ? sc[cc] : 0.01f * sc[cc];

  float mx = fmaxf(fmaxf(sc[0], sc[1]), fmaxf(sc[2], sc[3]));
  float ex[4], ssum = 0.f;
#pragma unroll
  for (int cc = 0; cc < 4; ++cc){ ex[cc] = expf(sc[cc] - mx); ssum += ex[cc]; }
  float o0 = 0.f, o1 = 0.f;
#pragma unroll
  for (int cc = 0; cc < 4; ++cc){
    float a = ex[cc] / ssum;
    o0 += a * c[cc][0];
    o1 += a * c[cc][1];
  }
  out[(long)b * D + e]     = o0;
  out[(long)b * D + e + 1] = o1;
}

extern "C" void kernel_launch(void* const* d_in, const int* in_sizes, int n_in,
                              void* d_out, int out_size, void* d_ws, size_t ws_size,
                              hipStream_t stream)
{
  const float* drug_feats = (const float*)d_in[0];   // [4000][1024]
  const float* gene_feats = (const float*)d_in[1];   // [20000][2048]
  const float* cell_tab   = (const float*)d_in[2];   // [2000][128]
  const float* W_drug     = (const float*)d_in[3];   // [1024][128]
  const float* b_drug     = (const float*)d_in[4];   // [128]
  const float* W_gene     = (const float*)d_in[5];   // [2048][128]
  const float* b_gene     = (const float*)d_in[6];   // [128]
  const float* rnn_Wx     = (const float*)d_in[7];   // [2][3][128][128]
  const float* rnn_Wh     = (const float*)d_in[8];
  const float* rnn_b      = (const float*)d_in[9];   // [2][3][128]
  const float* att_w      = (const float*)d_in[10];  // [2][256]
  const int* center_ids   = (const int*)d_in[11];    // [4096]
  const int* cell_neigh   = (const int*)d_in[12];    // [2][4096][10]
  const int* drug_neigh   = (const int*)d_in[13];
  const int* gene_neigh   = (const int*)d_in[14];

  // ws (u16 elems): WdT [128*1024] | WgT [128*2048] | agg [3*CB*128] | x [CB*10*128]
  // bytes needed = 786432 + 3328*CB; CB from ws_size (constant per call).
  int CB = 4096;
  while (CB > 64){
    size_t need = 786432 + (size_t)3328 * CB;
    if (need <= ws_size) break;
    CB >>= 1;
  }

  u16* ws  = (u16*)d_ws;
  u16* WdT = ws;
  u16* WgT = WdT + 128 * 1024;
  u16* agg = WgT + 128 * 2048;
  u16* x   = agg + (size_t)3 * CB * 128;
  float* h = (float*)d_out;               // f32 [4096][128] — h lives in d_out

  transpose_k<<<(1024 * D + 255) / 256, 256, 0, stream>>>(W_drug, WdT, 1024);
  transpose_k<<<(2048 * D + 255) / 256, 256, 0, stream>>>(W_gene, WgT, 2048);

  for (int b0 = 0; b0 < 4096; b0 += CB){
    // h0 = drug_feats[center_ids] @ W_drug + b_drug  (f32 into d_out rows)
    proj_gemm<<<CB / 64, 256, 0, stream>>>(drug_feats, 1024, 4000,
                                           center_ids + b0, WdT, b_drug,
                                           (u16*)nullptr, h + (size_t)b0 * D);
    for (int l = 0; l < 2; ++l){
      const int* cn = cell_neigh + ((size_t)l * 4096 + b0) * Ssz;
      const int* dn = drug_neigh + ((size_t)l * 4096 + b0) * Ssz;
      const int* gn = gene_neigh + ((size_t)l * 4096 + b0) * Ssz;
      const float* Wx = rnn_Wx + (size_t)l * 3 * D * D;
      const float* Wh = rnn_Wh + (size_t)l * 3 * D * D;
      const float* bb = rnn_b  + (size_t)l * 3 * D;

      // type 0: cell (raw table rows)
      gather_rows<<<CB * Ssz / 4, 256, 0, stream>>>(cell_tab, cn, x, CB * Ssz, 2000);
      rnn_kernel<<<CB / 16, 256, 0, stream>>>(x, Wx, Wh, bb, agg);
      // type 1: drug (gather + project)
      proj_gemm<<<CB * Ssz / 64, 256, 0, stream>>>(drug_feats, 1024, 4000, dn,
                                                   WdT, b_drug, x, (float*)nullptr);
      rnn_kernel<<<CB / 16, 256, 0, stream>>>(x, Wx + D * D, Wh + D * D, bb + D,
                                              agg + (size_t)CB * D);
      // type 2: gene
      proj_gemm<<<CB * Ssz / 64, 256, 0, stream>>>(gene_feats, 2048, 20000, gn,
                                                   WgT, b_gene, x, (float*)nullptr);
      rnn_kernel<<<CB / 16, 256, 0, stream>>>(x, Wx + 2 * D * D, Wh + 2 * D * D,
                                              bb + 2 * D, agg + (size_t)2 * CB * D);
      // attention combine (in-place over this chunk's h rows)
      att_kernel<<<CB / 4, 256, 0, stream>>>(h + (size_t)b0 * D, agg,
                                             att_w + (size_t)l * 2 * D,
                                             h + (size_t)b0 * D, CB);
    }
  }
}